// Round 7
// baseline (2508.046 us; speedup 1.0000x reference)
//
#include <hip/hip_runtime.h>
#include <stdint.h>

// LSTMTimeDecoder on MI355X — round 7.
// Round 6 lesson: exchange round trips were NOT dominant (3->1 trips bought
// only 6%). The floor is 1 wave/SIMD occupancy (zero latency hiding) + LDS
// pipe pressure from W_hh fragment reads. This round:
//   * W_hh fragments live in REGISTERS (128 VGPR/wave) — no Wlds, no
//     per-step W LDS reads. LDS/wg: 153KB -> 12KB.
//   * 512 wgs = 32 batch-groups (8 rows) x 16 members, __launch_bounds__(256,2)
//     -> 2 wgs/CU: two independent recurrences per CU hide each other's
//     exchange latency via TLP.
//   * Exchange: round-6 sentinel protocol verbatim (3-slot rotation,
//     pre-poisoned 0xFF80FF80, fused load+vmcnt asm, re-poison ordered by
//     the vmcnt(0) before the h store). Reload is 8KB/wg now.
// Partial-residency safe: group members are consecutive bids, so any
// residency prefix completes whole groups and retires (no deadlock).

#define HD 512
#define BD 256
#define SD 512
#define OD 128
#define SENT 0xFF80FF80u

typedef __attribute__((ext_vector_type(8))) short short8;
typedef __attribute__((ext_vector_type(4))) float f32x4;
typedef __attribute__((ext_vector_type(4))) unsigned int u32x4;

static __device__ __forceinline__ unsigned short f2bf(float x) {
  unsigned int u = __float_as_uint(x);
  u += 0x7fffu + ((u >> 16) & 1u);
  return (unsigned short)(u >> 16);
}
static __device__ __forceinline__ float sigm(float x) {
  return 1.0f / (1.0f + __expf(-x));
}
static __device__ __forceinline__ float tanhf_(float x) {
  x = fminf(15.f, fmaxf(-15.f, x));
  float e = __expf(2.f * x);
  return (e - 1.f) / (e + 1.f);
}
static __device__ __forceinline__ int badchk(u32x4 v) {
  return (v.x == SENT) | (v.y == SENT) | (v.z == SENT) | (v.w == SENT);
}

// ---------------- prep kernels ----------------
__global__ __launch_bounds__(256) void k_cvt(const float* __restrict__ whh,
                                             const float* __restrict__ linw,
                                             unsigned short* __restrict__ whhb,
                                             unsigned short* __restrict__ linwb) {
  int i = blockIdx.x * 256 + threadIdx.x;
  whhb[i] = f2bf(whh[i]);
  if (i < OD * HD) linwb[i] = f2bf(linw[i]);
}

__global__ __launch_bounds__(256) void k_u(const float* __restrict__ wih,
                                           const float* __restrict__ tw,
                                           const float* __restrict__ tb,
                                           const float* __restrict__ bih,
                                           const float* __restrict__ bhh,
                                           float* __restrict__ u,
                                           float* __restrict__ ub) {
  int gc = blockIdx.x * 256 + threadIdx.x;
  const float4* w4 = (const float4*)(wih + (size_t)gc * (2 * HD) + HD);
  const float4* t4 = (const float4*)tw;
  const float4* b4 = (const float4*)tb;
  float a = 0.f, b = 0.f;
  for (int k = 0; k < HD / 4; ++k) {
    float4 w = w4[k], tv = t4[k], bv = b4[k];
    a += w.x * tv.x + w.y * tv.y + w.z * tv.z + w.w * tv.w;
    b += w.x * bv.x + w.y * bv.y + w.z * bv.z + w.w * bv.w;
  }
  u[gc] = a;
  ub[gc] = b + bih[gc] + bhh[gc];
}

__global__ __launch_bounds__(1024) void k_cw(const float* __restrict__ C,
                                             const float* __restrict__ wih,
                                             const float* __restrict__ ub,
                                             float* __restrict__ CW) {
  int gc = blockIdx.x * 64 + (threadIdx.x & 63);
  int b  = blockIdx.y * 16 + (threadIdx.x >> 6);
  const float4* c4 = (const float4*)(C + (size_t)b * HD);
  const float4* w4 = (const float4*)(wih + (size_t)gc * (2 * HD));
  float acc = 0.f;
  for (int k = 0; k < HD / 4; ++k) {
    float4 cv = c4[k], wv = w4[k];
    acc += cv.x * wv.x + cv.y * wv.y + cv.z * wv.z + cv.w * wv.w;
  }
  CW[(size_t)b * (4 * HD) + gc] = acc + ub[gc];
}

// sentinel-poison the whole h exchange buffer (every launch => replay-safe)
__global__ __launch_bounds__(256) void k_poison(unsigned int* __restrict__ hbuf) {
  u32x4 s = {SENT, SENT, SENT, SENT};
  unsigned int* p = hbuf + (size_t)(blockIdx.x * 256 + threadIdx.x) * 4;
  asm volatile("global_store_dwordx4 %0, %1, off sc0 sc1" :: "v"(p), "v"(s) : "memory");
}

// ---------------- main recurrent kernel ----------------
__global__ __launch_bounds__(256, 2) void k_main(
    const float* __restrict__ CW, const float* __restrict__ u,
    const float* __restrict__ tarr, const unsigned short* __restrict__ whhb,
    const unsigned short* __restrict__ linwb, const float* __restrict__ linb,
    unsigned short* __restrict__ hbuf, float* __restrict__ out)
{
  __shared__ __align__(16) unsigned short hlds[8 * HD];   // 8KB, swizzled
  __shared__ float gbuf[4][8][33];                        // 4.2KB

  const int tid  = threadIdx.x;
  const int lane = tid & 63;
  const int wv   = tid >> 6;          // wave 0..3 == gate type i,f,g,o
  const int m    = blockIdx.x & 15;   // member: owns gate-cols [m*32, m*32+32)
  const int g    = blockIdx.x >> 4;   // batch group 0..31 (rows g*8..g*8+8)

  // ---- W_hh fragments -> REGISTERS (2 B-frags x 16 kk = 128 VGPRs) ----
  short8 w0[16], w1[16];
  {
    const unsigned short* wb =
        whhb + ((size_t)wv * HD + m * 32 + (lane & 15)) * HD + (lane >> 4) * 8;
    #pragma unroll
    for (int kk = 0; kk < 16; ++kk) {
      w0[kk] = *(const short8*)(wb + kk * 32);
      w1[kk] = *(const short8*)(wb + 16 * HD + kk * 32);
    }
  }

  // ---- cell mapping: 1 element/thread ----
  const int r    = tid >> 5;          // 0..7 (batch row within group)
  const int j    = tid & 31;          // col within member slice
  const int grow = g * 8 + r;
  float cwr[4], ur[4];
  #pragma unroll
  for (int gg = 0; gg < 4; ++gg) {
    int col = gg * HD + m * 32 + j;
    cwr[gg] = CW[(size_t)grow * (4 * HD) + col];
    ur[gg]  = u[col];
  }
  float cst = 0.f;

  const int wsel = 1 + (m % 3);       // designated out-projection wave (1..3)
  float lb = 0.f;
  const char* lwbase = nullptr;
  if (m < 8) {
    int oc = m * 16 + (lane & 15);
    lb = linb[oc];
    lwbase = (const char*)linwb + (size_t)oc * 1024;
  }

  short8 afrag[16];
  {
    short8 z = {0, 0, 0, 0, 0, 0, 0, 0};
    #pragma unroll
    for (int kk = 0; kk < 16; ++kk) afrag[kk] = z;   // h_0 = 0
  }

  // hbuf: [32 groups][3 slots][8 rows][512] bf16 ; slot(h_n) = n%3
  char* hb = (char*)hbuf + (size_t)g * (3 * 8 * HD * 2);  // 24KB per group

  const int arow  = lane & 7;         // rows 0..7 (lanes 8-15 duplicate: benign)
  const int asw   = arow << 4;
  const int koffB = (lane >> 4) * 16;

  float tcur = tarr[grow];   // t[0, b]
  float tdv  = 0.f;          // delta for step 0 is 0 by construction

  int sN = 1;                // (t+1)%3

  for (int t = 0; t < SD; ++t) {
    const int sP = (sN + 1 == 3) ? 0 : sN + 1;   // == (t-1)%3 for t>=2
    const size_t soN = (size_t)sN * 8192;

    // ---- re-poison h_{t-1}'s slot (my cols, all 8 rows): consumed by all ----
    if (t >= 2 && tid < 128) {
      unsigned int* pp = (unsigned int*)(hb + (size_t)sP * 8192 +
                                         (tid >> 4) * 1024 + m * 64 + (tid & 15) * 4);
      unsigned int s = SENT;
      asm volatile("global_store_dword %0, %1, off sc0 sc1" :: "v"(pp), "v"(s) : "memory");
    }

    // ---- gates = h_t @ Whh_slice^T (pure register MFMAs) ----
    f32x4 acc0 = {0.f, 0.f, 0.f, 0.f}, acc1 = {0.f, 0.f, 0.f, 0.f};
    #pragma unroll
    for (int kk = 0; kk < 16; ++kk) {
      acc0 = __builtin_amdgcn_mfma_f32_16x16x32_bf16(afrag[kk], w0[kk], acc0, 0, 0, 0);
      acc1 = __builtin_amdgcn_mfma_f32_16x16x32_bf16(afrag[kk], w1[kk], acc1, 0, 0, 0);
    }
    {
      int rr = (lane >> 4) * 4, cc = lane & 15;
      if (rr < 8) {                    // D rows 0..7 are the real batch rows
        #pragma unroll
        for (int q = 0; q < 4; ++q) {
          gbuf[wv][rr + q][cc]      = acc0[q];
          gbuf[wv][rr + q][16 + cc] = acc1[q];
        }
      }
    }
    __syncthreads();  // B1: gates visible in gbuf

    // ---- LSTM cell update (1 element/thread) ----
    {
      float pi = gbuf[0][r][j] + cwr[0] + tdv * ur[0];
      float pf = gbuf[1][r][j] + cwr[1] + tdv * ur[1];
      float pg = gbuf[2][r][j] + cwr[2] + tdv * ur[2];
      float po = gbuf[3][r][j] + cwr[3] + tdv * ur[3];
      cst = sigm(pf) * cst + sigm(pi) * tanhf_(pg);
      float h = sigm(po) * tanhf_(cst);
      unsigned int hu = (unsigned int)f2bf(h);
      unsigned int other = (unsigned int)__shfl_xor((int)hu, 1, 64);
      // order: re-poison (old slot) must be at L3 before this store is visible
      asm volatile("s_waitcnt vmcnt(0)" ::: "memory");
      if ((tid & 1) == 0) {
        unsigned int hp = hu | (other << 16);
        unsigned int* hslot = (unsigned int*)(hb + soN + (size_t)(r * HD + m * 32 + j) * 2);
        asm volatile("global_store_dword %0, %1, off sc0 sc1" :: "v"(hslot), "v"(hp) : "memory");
      }
    }

    // prefetch next t value (consumed at loop bottom)
    float tn = (t + 1 < SD) ? tarr[(size_t)(t + 1) * BD + grow] : 0.f;

    // ---- out row t-1 (afrag still = h_t); rides the poll window ----
    if (wv == wsel && m < 8 && t > 0) {
      f32x4 osum = {0.f, 0.f, 0.f, 0.f};
      #pragma unroll
      for (int kk = 0; kk < 16; ++kk) {
        short8 bf = *(const short8*)(lwbase + kk * 64 + koffB);
        osum = __builtin_amdgcn_mfma_f32_16x16x32_bf16(afrag[kk], bf, osum, 0, 0, 0);
      }
      int rr = (lane >> 4) * 4, cc = lane & 15;
      if (rr < 8) {
        float* ob = out + (size_t)(t - 1) * (BD * OD) + (size_t)(g * 8) * OD + m * 16;
        #pragma unroll
        for (int q = 0; q < 4; ++q)
          ob[(size_t)(rr + q) * OD + cc] = osum[q] + lb;
      }
    }

    // ---- fused poll+reload of h_{t+1} (8KB): sentinel retry; loads+vmcnt
    //      in ONE asm block (rule #18) ----
    u32x4 v0, v1;
    {
      const char* src = hb + soN + (size_t)tid * 32;
      int guard = 0;
      for (;;) {
        asm volatile(
            "global_load_dwordx4 %0, %2, off sc0 sc1\n\t"
            "global_load_dwordx4 %1, %3, off sc0 sc1\n\t"
            "s_waitcnt vmcnt(0)"
            : "=&v"(v0), "=&v"(v1)
            : "v"(src), "v"(src + 16)
            : "memory");
        __builtin_amdgcn_sched_barrier(0);
        if (!(badchk(v0) | badchk(v1))) break;
        if (++guard > (1 << 14)) break;  // bounded: garbage-not-hang
      }
    }
    __builtin_amdgcn_sched_barrier(0);

    // ---- scatter h_{t+1} into LDS (swizzled) ----
    {
      int row  = tid >> 5;
      int colb = (tid & 31) * 32;
      *(u32x4*)((char*)hlds + row * 1024 + (colb ^ (row << 4)))        = v0;
      *(u32x4*)((char*)hlds + row * 1024 + ((colb + 16) ^ (row << 4))) = v1;
    }
    __syncthreads();  // B4: hlds ready

    // ---- refresh A-frags (h_{t+1}) ----
    #pragma unroll
    for (int kk = 0; kk < 16; ++kk) {
      int kb = kk * 64 + koffB;
      afrag[kk] = *(const short8*)((const char*)hlds + arow * 1024 + (kb ^ asw));
    }

    // ---- advance time delta ----
    tdv  = tn - tcur;
    tcur = tn;
    sN   = (sN + 1 == 3) ? 0 : sN + 1;
  }

  // ---- tail: out row SD-1 (afrag = h_SD) ----
  if (m < 8 && wv == wsel) {
    f32x4 osum = {0.f, 0.f, 0.f, 0.f};
    #pragma unroll
    for (int kk = 0; kk < 16; ++kk) {
      short8 bf = *(const short8*)(lwbase + kk * 64 + koffB);
      osum = __builtin_amdgcn_mfma_f32_16x16x32_bf16(afrag[kk], bf, osum, 0, 0, 0);
    }
    int rr = (lane >> 4) * 4, cc = lane & 15;
    if (rr < 8) {
      float* ob = out + (size_t)(SD - 1) * (BD * OD) + (size_t)(g * 8) * OD + m * 16;
      #pragma unroll
      for (int q = 0; q < 4; ++q)
        ob[(size_t)(rr + q) * OD + cc] = osum[q] + lb;
    }
  }
}

// ---------------- launcher ----------------
extern "C" void kernel_launch(void* const* d_in, const int* in_sizes, int n_in,
                              void* d_out, int out_size, void* d_ws, size_t ws_size,
                              hipStream_t stream) {
  const float* C    = (const float*)d_in[0];
  const float* t    = (const float*)d_in[1];
  // d_in[2] = mask (unused by reference)
  const float* Wih  = (const float*)d_in[3];
  const float* Whh  = (const float*)d_in[4];
  const float* bih  = (const float*)d_in[5];
  const float* bhh  = (const float*)d_in[6];
  const float* linW = (const float*)d_in[7];
  const float* linb = (const float*)d_in[8];
  const float* tW   = (const float*)d_in[9];
  const float* tb   = (const float*)d_in[10];
  float* out = (float*)d_out;

  char* ws = (char*)d_ws;
  float*          CW    = (float*)(ws + 0);                 // 2,097,152
  float*          u     = (float*)(ws + 2097152);           // 8,192
  float*          ub    = (float*)(ws + 2105344);           // 8,192
  unsigned short* whhb  = (unsigned short*)(ws + 2113536);  // 2,097,152
  unsigned short* linwb = (unsigned short*)(ws + 4210688);  // 131,072
  unsigned short* hbuf  = (unsigned short*)(ws + 4341760);  // 32*3*8*512*2 = 786,432
  if (ws_size < 5128192) return;

  k_poison<<<192, 256, 0, stream>>>((unsigned int*)hbuf);
  k_cvt<<<4096, 256, 0, stream>>>(Whh, linW, whhb, linwb);
  k_u  <<<8, 256, 0, stream>>>(Wih, tW, tb, bih, bhh, u, ub);
  k_cw <<<dim3(32, 16), 1024, 0, stream>>>(C, Wih, ub, CW);
  k_main<<<512, 256, 0, stream>>>(CW, u, t, whhb, linwb, linb, hbuf, out);
}

// Round 9
// 2385.243 us; speedup vs baseline: 1.0515x; 1.0515x over previous
//
#include <hip/hip_runtime.h>
#include <stdint.h>

// LSTMTimeDecoder on MI355X — round 9.
// Round 8 lesson (2nd plain-store failure): the sentinel protocol DOES have a
// cross-thread ordering edge — repoison(slot, step t) must reach the coherence
// point before peers' data stores to the same slot at t+1. Only sc0sc1 ops +
// vmcnt(0) (= "at L3") give that. All cross-CU traffic stays device-scope.
// This round keeps round 6's proven protocol and attacks the measured residual:
//   * W_hh in REGISTERS (round 7's verified piece): no Wlds, no per-step
//     ds_read_b128 waits in the gates loop. LDS ~25KB.
//   * Poll discipline: calibrated delay before first poll (out-proj on wsel,
//     s_sleep(4) on other waves) so the first 16KB fused load usually
//     succeeds; retries are exec-masked PER-CHUNK reloads with s_sleep(1)
//     backoff (issue-all -> one waitcnt -> sched_barrier(0), rule #18).

#define HD 512
#define BD 256
#define SD 512
#define OD 128
#define SENT 0xFF80FF80u

typedef __attribute__((ext_vector_type(8))) short short8;
typedef __attribute__((ext_vector_type(4))) float f32x4;
typedef __attribute__((ext_vector_type(4))) unsigned int u32x4;

static __device__ __forceinline__ unsigned short f2bf(float x) {
  unsigned int u = __float_as_uint(x);
  u += 0x7fffu + ((u >> 16) & 1u);
  return (unsigned short)(u >> 16);
}
static __device__ __forceinline__ float sigm(float x) {
  return 1.0f / (1.0f + __expf(-x));
}
static __device__ __forceinline__ float tanhf_(float x) {
  x = fminf(15.f, fmaxf(-15.f, x));
  float e = __expf(2.f * x);
  return (e - 1.f) / (e + 1.f);
}
static __device__ __forceinline__ int badchk(u32x4 v) {
  return (v.x == SENT) | (v.y == SENT) | (v.z == SENT) | (v.w == SENT);
}

// ---------------- prep kernels ----------------
__global__ __launch_bounds__(256) void k_cvt(const float* __restrict__ whh,
                                             const float* __restrict__ linw,
                                             unsigned short* __restrict__ whhb,
                                             unsigned short* __restrict__ linwb) {
  int i = blockIdx.x * 256 + threadIdx.x;
  whhb[i] = f2bf(whh[i]);
  if (i < OD * HD) linwb[i] = f2bf(linw[i]);
}

__global__ __launch_bounds__(256) void k_u(const float* __restrict__ wih,
                                           const float* __restrict__ tw,
                                           const float* __restrict__ tb,
                                           const float* __restrict__ bih,
                                           const float* __restrict__ bhh,
                                           float* __restrict__ u,
                                           float* __restrict__ ub) {
  int gc = blockIdx.x * 256 + threadIdx.x;
  const float4* w4 = (const float4*)(wih + (size_t)gc * (2 * HD) + HD);
  const float4* t4 = (const float4*)tw;
  const float4* b4 = (const float4*)tb;
  float a = 0.f, b = 0.f;
  for (int k = 0; k < HD / 4; ++k) {
    float4 w = w4[k], tv = t4[k], bv = b4[k];
    a += w.x * tv.x + w.y * tv.y + w.z * tv.z + w.w * tv.w;
    b += w.x * bv.x + w.y * bv.y + w.z * bv.z + w.w * bv.w;
  }
  u[gc] = a;
  ub[gc] = b + bih[gc] + bhh[gc];
}

__global__ __launch_bounds__(1024) void k_cw(const float* __restrict__ C,
                                             const float* __restrict__ wih,
                                             const float* __restrict__ ub,
                                             float* __restrict__ CW) {
  int gc = blockIdx.x * 64 + (threadIdx.x & 63);
  int b  = blockIdx.y * 16 + (threadIdx.x >> 6);
  const float4* c4 = (const float4*)(C + (size_t)b * HD);
  const float4* w4 = (const float4*)(wih + (size_t)gc * (2 * HD));
  float acc = 0.f;
  for (int k = 0; k < HD / 4; ++k) {
    float4 cv = c4[k], wv = w4[k];
    acc += cv.x * wv.x + cv.y * wv.y + cv.z * wv.z + cv.w * wv.w;
  }
  CW[(size_t)b * (4 * HD) + gc] = acc + ub[gc];
}

// sentinel-poison the whole h exchange buffer (every launch => replay-safe)
__global__ __launch_bounds__(256) void k_poison(unsigned int* __restrict__ hbuf) {
  u32x4 s = {SENT, SENT, SENT, SENT};
  unsigned int* p = hbuf + (size_t)(blockIdx.x * 256 + threadIdx.x) * 4;
  asm volatile("global_store_dwordx4 %0, %1, off sc0 sc1" :: "v"(p), "v"(s) : "memory");
}

// ---------------- main recurrent kernel ----------------
__global__ __launch_bounds__(256, 1) void k_main(
    const float* __restrict__ CW, const float* __restrict__ u,
    const float* __restrict__ tarr, const unsigned short* __restrict__ whhb,
    const unsigned short* __restrict__ linwb, const float* __restrict__ linb,
    unsigned short* __restrict__ hbuf, float* __restrict__ out)
{
  __shared__ __align__(16) unsigned short hlds[16 * HD];  // 16KB, swizzled
  __shared__ float gbuf[4][16][33];

  const int tid  = threadIdx.x;
  const int lane = tid & 63;
  const int wv   = tid >> 6;          // wave 0..3 == gate type i,f,g,o
  const int gid  = blockIdx.x & 15;   // batch group
  const int m    = blockIdx.x >> 4;   // member: owns h-cols [m*32, m*32+32)

  // ---- W_hh fragments -> REGISTERS (2 B-frags x 16 kk = 128 VGPRs) ----
  // (layout verified in round 7)
  short8 w0[16], w1[16];
  {
    const unsigned short* wb =
        whhb + ((size_t)wv * HD + m * 32 + (lane & 15)) * HD + (lane >> 4) * 8;
    #pragma unroll
    for (int kk = 0; kk < 16; ++kk) {
      w0[kk] = *(const short8*)(wb + kk * 32);
      w1[kk] = *(const short8*)(wb + 16 * HD + kk * 32);
    }
  }

  // ---- step-invariant per-thread state (2 cell elems/thread) ----
  const int r    = tid >> 4;
  const int jl0  = (tid & 15) * 2;
  const int grow = gid * 16 + r;
  float cwr[8], ur[8];
  #pragma unroll
  for (int g = 0; g < 4; ++g) {
    int col = g * HD + m * 32 + jl0;
    cwr[g * 2]     = CW[(size_t)grow * (4 * HD) + col];
    cwr[g * 2 + 1] = CW[(size_t)grow * (4 * HD) + col + 1];
    ur[g * 2]      = u[col];
    ur[g * 2 + 1]  = u[col + 1];
  }
  float c0 = 0.f, c1 = 0.f;

  const int wsel = 1 + (m % 3);       // designated out-projection wave (1..3)
  float lb = 0.f;
  const char* lwbase = nullptr;
  if (m < 8) {
    int oc = m * 16 + (lane & 15);
    lb = linb[oc];
    lwbase = (const char*)linwb + (size_t)oc * 1024;
  }

  short8 afrag[16];
  {
    short8 z = {0, 0, 0, 0, 0, 0, 0, 0};
    #pragma unroll
    for (int kk = 0; kk < 16; ++kk) afrag[kk] = z;   // h_0 = 0
  }

  // hbuf: [16 groups][3 slots][16 rows][512] bf16 ; slot(h_n) = n%3
  char* hb = (char*)hbuf + (size_t)gid * (3 * 16 * HD * 2);   // 48KB/group

  const int koff = (lane >> 4) * 16;
  const int arow = lane & 15;
  const int asw  = (arow & 7) << 4;

  float tcur = tarr[grow];   // t[0, b]
  float tdv  = 0.f;          // delta for step 0 is 0 by construction

  __syncthreads();

  int sN = 1;                // (t+1)%3

  for (int t = 0; t < SD; ++t) {
    const int sP = (sN + 1 == 3) ? 0 : sN + 1;   // == (t-1)%3 for t>=2
    const size_t soN = (size_t)sN * 16384;

    // ---- re-poison h_{t-1}'s slot (my 1/16): provably consumed by all ----
    if (t >= 2) {
      unsigned int* pp = (unsigned int*)(hb + (size_t)sP * 16384 + m * 1024 + tid * 4);
      unsigned int s = SENT;
      asm volatile("global_store_dword %0, %1, off sc0 sc1" :: "v"(pp), "v"(s) : "memory");
    }

    // ---- gates = h_t @ Whh_slice^T (pure register MFMAs) ----
    f32x4 acc0 = {0.f, 0.f, 0.f, 0.f}, acc1 = {0.f, 0.f, 0.f, 0.f};
    #pragma unroll
    for (int kk = 0; kk < 16; ++kk) {
      acc0 = __builtin_amdgcn_mfma_f32_16x16x32_bf16(afrag[kk], w0[kk], acc0, 0, 0, 0);
      acc1 = __builtin_amdgcn_mfma_f32_16x16x32_bf16(afrag[kk], w1[kk], acc1, 0, 0, 0);
    }
    {
      int rr = (lane >> 4) * 4, cc = lane & 15;
      #pragma unroll
      for (int q = 0; q < 4; ++q) {
        gbuf[wv][rr + q][cc]      = acc0[q];
        gbuf[wv][rr + q][16 + cc] = acc1[q];
      }
    }
    __syncthreads();  // B1: gates visible in gbuf

    // ---- LSTM cell update (2 elements/thread) ----
    {
      float p0i = gbuf[0][r][jl0]     + cwr[0] + tdv * ur[0];
      float p1i = gbuf[0][r][jl0 + 1] + cwr[1] + tdv * ur[1];
      float p0f = gbuf[1][r][jl0]     + cwr[2] + tdv * ur[2];
      float p1f = gbuf[1][r][jl0 + 1] + cwr[3] + tdv * ur[3];
      float p0g = gbuf[2][r][jl0]     + cwr[4] + tdv * ur[4];
      float p1g = gbuf[2][r][jl0 + 1] + cwr[5] + tdv * ur[5];
      float p0o = gbuf[3][r][jl0]     + cwr[6] + tdv * ur[6];
      float p1o = gbuf[3][r][jl0 + 1] + cwr[7] + tdv * ur[7];
      c0 = sigm(p0f) * c0 + sigm(p0i) * tanhf_(p0g);
      c1 = sigm(p1f) * c1 + sigm(p1i) * tanhf_(p1g);
      float h0 = sigm(p0o) * tanhf_(c0);
      float h1 = sigm(p1o) * tanhf_(c1);
      unsigned int hp = (unsigned int)f2bf(h0) | ((unsigned int)f2bf(h1) << 16);
      // drain: repoison must be AT L3 before this (future same-addr) store
      asm volatile("s_waitcnt vmcnt(0)" ::: "memory");
      unsigned int* hslot = (unsigned int*)(hb + soN + (size_t)(r * HD + m * 32 + jl0) * 2);
      asm volatile("global_store_dword %0, %1, off sc0 sc1" :: "v"(hslot), "v"(hp) : "memory");
    }

    // prefetch next t value (consumed at loop bottom)
    float tn = (t + 1 < SD) ? tarr[(size_t)(t + 1) * BD + grow] : 0.f;

    // ---- delay window: out-proj (wsel) or calibrated sleep (others) so the
    //      first poll lands after peers' stores are visible ----
    if (wv == wsel && m < 8 && t > 0) {
      f32x4 osum = {0.f, 0.f, 0.f, 0.f};
      #pragma unroll
      for (int kk = 0; kk < 16; ++kk) {
        short8 bf = *(const short8*)(lwbase + kk * 64 + koff);
        osum = __builtin_amdgcn_mfma_f32_16x16x32_bf16(afrag[kk], bf, osum, 0, 0, 0);
      }
      float* ob = out + (size_t)(t - 1) * (BD * OD) + (size_t)(gid * 16) * OD + m * 16;
      int rr = (lane >> 4) * 4, cc = lane & 15;
      #pragma unroll
      for (int q = 0; q < 4; ++q)
        ob[(size_t)(rr + q) * OD + cc] = osum[q] + lb;
    } else {
      __builtin_amdgcn_s_sleep(4);   // ~256 cy
    }

    // ---- poll+reload of h_{t+1}: fused first try; masked per-chunk retries ----
    u32x4 v0, v1, v2, v3;
    {
      const char* src = hb + soN + (size_t)tid * 16;
      asm volatile(
          "global_load_dwordx4 %0, %4, off sc0 sc1\n\t"
          "global_load_dwordx4 %1, %5, off sc0 sc1\n\t"
          "global_load_dwordx4 %2, %6, off sc0 sc1\n\t"
          "global_load_dwordx4 %3, %7, off sc0 sc1\n\t"
          "s_waitcnt vmcnt(0)"
          : "=&v"(v0), "=&v"(v1), "=&v"(v2), "=&v"(v3)
          : "v"(src), "v"(src + 4096), "v"(src + 8192), "v"(src + 12288)
          : "memory");
      __builtin_amdgcn_sched_barrier(0);
      int p0 = badchk(v0), p1 = badchk(v1), p2 = badchk(v2), p3 = badchk(v3);
      int guard = 0;
      while (p0 | p1 | p2 | p3) {
        if (++guard > (1 << 16)) break;  // bounded: garbage-not-hang
        __builtin_amdgcn_s_sleep(1);     // backoff ~64 cy
        // exec-masked per-chunk reissue: only stale pieces reload
        if (p0) asm volatile("global_load_dwordx4 %0, %1, off sc0 sc1" : "=&v"(v0) : "v"(src) : "memory");
        if (p1) asm volatile("global_load_dwordx4 %0, %1, off sc0 sc1" : "=&v"(v1) : "v"(src + 4096) : "memory");
        if (p2) asm volatile("global_load_dwordx4 %0, %1, off sc0 sc1" : "=&v"(v2) : "v"(src + 8192) : "memory");
        if (p3) asm volatile("global_load_dwordx4 %0, %1, off sc0 sc1" : "=&v"(v3) : "v"(src + 12288) : "memory");
        asm volatile("s_waitcnt vmcnt(0)" ::: "memory");
        __builtin_amdgcn_sched_barrier(0);  // rule #18: no hoisting past the wait
        p0 = badchk(v0); p1 = badchk(v1); p2 = badchk(v2); p3 = badchk(v3);
      }
    }
    __builtin_amdgcn_sched_barrier(0);

    // ---- scatter h_{t+1} into LDS (swizzled) ----
    {
      const int c = tid & 63;
      { int rr = wv;      *(u32x4*)((char*)hlds + (size_t)rr * 1024 + (size_t)((c ^ (rr & 7)) * 16)) = v0; }
      { int rr = wv + 4;  *(u32x4*)((char*)hlds + (size_t)rr * 1024 + (size_t)((c ^ (rr & 7)) * 16)) = v1; }
      { int rr = wv + 8;  *(u32x4*)((char*)hlds + (size_t)rr * 1024 + (size_t)((c ^ (rr & 7)) * 16)) = v2; }
      { int rr = wv + 12; *(u32x4*)((char*)hlds + (size_t)rr * 1024 + (size_t)((c ^ (rr & 7)) * 16)) = v3; }
    }
    __syncthreads();  // B4: hlds ready

    // ---- refresh A-frags (h_{t+1}) ----
    #pragma unroll
    for (int kk = 0; kk < 16; ++kk) {
      int kb = kk * 64 + koff;
      afrag[kk] = *(const short8*)((const char*)hlds + (size_t)arow * 1024 + (kb ^ asw));
    }

    // ---- advance time delta ----
    tdv  = tn - tcur;
    tcur = tn;
    sN   = (sN + 1 == 3) ? 0 : sN + 1;
  }

  // ---- tail: out row SD-1 (afrag = h_SD) ----
  if (m < 8 && wv == wsel) {
    f32x4 osum = {0.f, 0.f, 0.f, 0.f};
    #pragma unroll
    for (int kk = 0; kk < 16; ++kk) {
      short8 bf = *(const short8*)(lwbase + kk * 64 + koff);
      osum = __builtin_amdgcn_mfma_f32_16x16x32_bf16(afrag[kk], bf, osum, 0, 0, 0);
    }
    float* ob = out + (size_t)(SD - 1) * (BD * OD) + (size_t)(gid * 16) * OD + m * 16;
    int rr = (lane >> 4) * 4, cc = lane & 15;
    #pragma unroll
    for (int q = 0; q < 4; ++q)
      ob[(size_t)(rr + q) * OD + cc] = osum[q] + lb;
  }
}

// ---------------- launcher ----------------
extern "C" void kernel_launch(void* const* d_in, const int* in_sizes, int n_in,
                              void* d_out, int out_size, void* d_ws, size_t ws_size,
                              hipStream_t stream) {
  const float* C    = (const float*)d_in[0];
  const float* t    = (const float*)d_in[1];
  // d_in[2] = mask (unused by reference)
  const float* Wih  = (const float*)d_in[3];
  const float* Whh  = (const float*)d_in[4];
  const float* bih  = (const float*)d_in[5];
  const float* bhh  = (const float*)d_in[6];
  const float* linW = (const float*)d_in[7];
  const float* linb = (const float*)d_in[8];
  const float* tW   = (const float*)d_in[9];
  const float* tb   = (const float*)d_in[10];
  float* out = (float*)d_out;

  char* ws = (char*)d_ws;
  float*          CW    = (float*)(ws + 0);                 // 2,097,152
  float*          u     = (float*)(ws + 2097152);           // 8,192
  float*          ub    = (float*)(ws + 2105344);           // 8,192
  unsigned short* whhb  = (unsigned short*)(ws + 2113536);  // 2,097,152
  unsigned short* linwb = (unsigned short*)(ws + 4210688);  // 131,072
  unsigned short* hbuf  = (unsigned short*)(ws + 4341760);  // 16*3*16*512*2 = 786,432
  if (ws_size < 5128192) return;

  k_poison<<<192, 256, 0, stream>>>((unsigned int*)hbuf);
  k_cvt<<<4096, 256, 0, stream>>>(Whh, linW, whhb, linwb);
  k_u  <<<8, 256, 0, stream>>>(Wih, tW, tb, bih, bhh, u, ub);
  k_cw <<<dim3(32, 16), 1024, 0, stream>>>(C, Wih, ub, CW);
  k_main<<<256, 256, 0, stream>>>(CW, u, t, whhb, linwb, linb, hbuf, out);
}

// Round 10
// 2028.758 us; speedup vs baseline: 1.2362x; 1.1757x over previous
//
#include <hip/hip_runtime.h>
#include <stdint.h>

// LSTMTimeDecoder on MI355X — round 10.
// Round 9 diagnosis: (a) VGPR_Count=136 proves the compiler never kept W_hh in
// registers (rematerialized loads) — rounds 7/9's change was a no-op; (b) every
// __syncthreads emits s_waitcnt vmcnt(0) => each of the 2 per-step barriers
// silently drained a ~900cy device-scope round trip. THAT was the unexplained
// 2-3k cy/step.
// This round: counted-everything.
//  * Raw s_barrier + explicit lgkmcnt(0) (no vmcnt drain at barriers).
//  * ALL in-loop global VMEM via inline asm in a fixed order
//    (tarr -> repoison -> prefetch x4 -> h-store -> out-stores) so every wait
//    is a counted vmcnt(N). No vmcnt(0) in steady state.
//  * G=2 group pipelining: each wg serves 2 batch-groups; next slot's h loads
//    prefetched mid-slot => poll RT hides under the other group's compute.
//    Sentinel protocol (3 slots, 0xFF80FF80) carried over verbatim.
//  * W_hh in LDS (round-6-proven); linW frags force-loaded to regs via asm.

#define HD 512
#define BD 256
#define SD 512
#define OD 128
#define SENT 0xFF80FF80u

typedef __attribute__((ext_vector_type(8))) short short8;
typedef __attribute__((ext_vector_type(4))) float f32x4;
typedef __attribute__((ext_vector_type(4))) unsigned int u32x4;

static __device__ __forceinline__ unsigned short f2bf(float x) {
  unsigned int u = __float_as_uint(x);
  u += 0x7fffu + ((u >> 16) & 1u);
  return (unsigned short)(u >> 16);
}
static __device__ __forceinline__ float sigm(float x) {
  return 1.0f / (1.0f + __expf(-x));
}
static __device__ __forceinline__ float tanhf_(float x) {
  x = fminf(15.f, fmaxf(-15.f, x));
  float e = __expf(2.f * x);
  return (e - 1.f) / (e + 1.f);
}
static __device__ __forceinline__ int badchk(u32x4 v) {
  return (v.x == SENT) | (v.y == SENT) | (v.z == SENT) | (v.w == SENT);
}
static __device__ __forceinline__ int badchk8(short8 v) {
  u32x4 w;
  __builtin_memcpy(&w, &v, 16);
  return badchk(w);
}
#define KEEPALIVE(x) asm volatile("" : "+v"(x))

// ---------------- prep kernels (verified rounds 1-9) ----------------
__global__ __launch_bounds__(256) void k_cvt(const float* __restrict__ whh,
                                             const float* __restrict__ linw,
                                             unsigned short* __restrict__ whhb,
                                             unsigned short* __restrict__ linwb) {
  int i = blockIdx.x * 256 + threadIdx.x;
  whhb[i] = f2bf(whh[i]);
  if (i < OD * HD) linwb[i] = f2bf(linw[i]);
}

__global__ __launch_bounds__(256) void k_u(const float* __restrict__ wih,
                                           const float* __restrict__ tw,
                                           const float* __restrict__ tb,
                                           const float* __restrict__ bih,
                                           const float* __restrict__ bhh,
                                           float* __restrict__ u,
                                           float* __restrict__ ub) {
  int gc = blockIdx.x * 256 + threadIdx.x;
  const float4* w4 = (const float4*)(wih + (size_t)gc * (2 * HD) + HD);
  const float4* t4 = (const float4*)tw;
  const float4* b4 = (const float4*)tb;
  float a = 0.f, b = 0.f;
  for (int k = 0; k < HD / 4; ++k) {
    float4 w = w4[k], tv = t4[k], bv = b4[k];
    a += w.x * tv.x + w.y * tv.y + w.z * tv.z + w.w * tv.w;
    b += w.x * bv.x + w.y * bv.y + w.z * bv.z + w.w * bv.w;
  }
  u[gc] = a;
  ub[gc] = b + bih[gc] + bhh[gc];
}

__global__ __launch_bounds__(1024) void k_cw(const float* __restrict__ C,
                                             const float* __restrict__ wih,
                                             const float* __restrict__ ub,
                                             float* __restrict__ CW) {
  int gc = blockIdx.x * 64 + (threadIdx.x & 63);
  int b  = blockIdx.y * 16 + (threadIdx.x >> 6);
  const float4* c4 = (const float4*)(C + (size_t)b * HD);
  const float4* w4 = (const float4*)(wih + (size_t)gc * (2 * HD));
  float acc = 0.f;
  for (int k = 0; k < HD / 4; ++k) {
    float4 cv = c4[k], wv = w4[k];
    acc += cv.x * wv.x + cv.y * wv.y + cv.z * wv.z + cv.w * wv.w;
  }
  CW[(size_t)b * (4 * HD) + gc] = acc + ub[gc];
}

__global__ __launch_bounds__(256) void k_poison(unsigned int* __restrict__ hbuf) {
  u32x4 s = {SENT, SENT, SENT, SENT};
  unsigned int* p = hbuf + (size_t)(blockIdx.x * 256 + threadIdx.x) * 4;
  asm volatile("global_store_dwordx4 %0, %1, off sc0 sc1" :: "v"(p), "v"(s) : "memory");
}

// ---------------- main recurrent kernel ----------------
__global__ __launch_bounds__(256, 1) void k_main(
    const float* __restrict__ CW, const float* __restrict__ u,
    const float* __restrict__ tarr, const unsigned short* __restrict__ whhb,
    const unsigned short* __restrict__ linwb, const float* __restrict__ linb,
    unsigned short* __restrict__ hbuf, float* __restrict__ out)
{
  __shared__ __align__(16) unsigned short Wlds[128 * HD]; // 128KB, swizzled
  __shared__ __align__(16) unsigned short hlds[16 * HD];  // 16KB, swizzled
  __shared__ float gbuf[4][16][33];                       // 8.25KB

  const int tid  = threadIdx.x;
  const int lane = tid & 63;
  const int wv   = tid >> 6;
  const int m    = blockIdx.x & 15;     // member: h-cols [m*32, m*32+32)
  const int q    = blockIdx.x >> 4;     // 0..7
  const int g0   = q, g1 = q + 8;       // the two batch groups of this wg

  // --- stage W_hh slice into LDS (round 6 verbatim) ---
  for (int i = tid; i < 128 * 64; i += 256) {
    int rl = i >> 6, c = i & 63;
    int gr = ((rl >> 5) * HD) + m * 32 + (rl & 31);
    int cs = c ^ (rl & 7);
    *(short8*)((char*)Wlds + (size_t)rl * 1024 + (size_t)c * 16) =
        *(const short8*)((const char*)whhb + (size_t)gr * 1024 + (size_t)cs * 16);
  }

  // --- step-invariant per-thread state ---
  const int r     = tid >> 4;
  const int jl0   = (tid & 15) * 2;
  const int grow0 = g0 * 16 + r;
  const int grow1 = g1 * 16 + r;
  float cwr0[8], cwr1[8], ur[8];
  #pragma unroll
  for (int g = 0; g < 4; ++g) {
    int col = g * HD + m * 32 + jl0;
    cwr0[g * 2]     = CW[(size_t)grow0 * (4 * HD) + col];
    cwr0[g * 2 + 1] = CW[(size_t)grow0 * (4 * HD) + col + 1];
    cwr1[g * 2]     = CW[(size_t)grow1 * (4 * HD) + col];
    cwr1[g * 2 + 1] = CW[(size_t)grow1 * (4 * HD) + col + 1];
    ur[g * 2]       = u[col];
    ur[g * 2 + 1]   = u[col + 1];
  }
  float c00 = 0.f, c01 = 0.f, c10 = 0.f, c11 = 0.f;

  const int  wsel  = 1 + (m % 3);
  const bool owsel = (m < 8) && (wv == wsel);
  float lb = 0.f;
  if (m < 8) lb = linb[m * 16 + (lane & 15)];

  // --- linW fragments FORCE-loaded to registers via asm (only out-proj wave) ---
  short8 lw[16];
  if (owsel) {
    const char* lwb = (const char*)linwb +
        (size_t)(m * 16 + (lane & 15)) * 1024 + (lane >> 4) * 16;
    #pragma unroll
    for (int b4 = 0; b4 < 4; ++b4) {
      asm volatile(
          "global_load_dwordx4 %0, %4, off\n\t"
          "global_load_dwordx4 %1, %5, off\n\t"
          "global_load_dwordx4 %2, %6, off\n\t"
          "global_load_dwordx4 %3, %7, off"
          : "=&v"(lw[b4 * 4]), "=&v"(lw[b4 * 4 + 1]),
            "=&v"(lw[b4 * 4 + 2]), "=&v"(lw[b4 * 4 + 3])
          : "v"(lwb + (b4 * 4 + 0) * 64), "v"(lwb + (b4 * 4 + 1) * 64),
            "v"(lwb + (b4 * 4 + 2) * 64), "v"(lwb + (b4 * 4 + 3) * 64)
          : "memory");
    }
    asm volatile("s_waitcnt vmcnt(0)" ::: "memory");
    __builtin_amdgcn_sched_barrier(0);
  }

  short8 afrag[16];
  u32x4 vp0, vp1, vp2, vp3;   // prefetched h chunks (next slot's consume)

  char* hb0 = (char*)hbuf + (size_t)g0 * 49152;  // 3 slots x 16KB
  char* hb1 = (char*)hbuf + (size_t)g1 * 49152;

  const int koff = (lane >> 4) * 16;
  const int arow = lane & 15;
  const int asw  = (arow & 7) << 4;
  const int row0 = wv * 32 + (lane & 15);
  const int row1 = row0 + 16;
  const int sw0  = (row0 & 7) << 4;
  const int sw1  = (row1 & 7) << 4;

  float tcur0 = tarr[grow0], tcur1 = tarr[grow1];
  float tdv0 = 0.f, tdv1 = 0.f;

  // pin pre-loop compiler loads into registers NOW (no in-loop compiler waits)
  #pragma unroll
  for (int i = 0; i < 8; ++i) { KEEPALIVE(cwr0[i]); KEEPALIVE(cwr1[i]); KEEPALIVE(ur[i]); }
  KEEPALIVE(lb); KEEPALIVE(tcur0); KEEPALIVE(tcur1);

  __syncthreads();   // pre-loop full barrier (drain is fine here, once)

  // ---- one pipeline slot ----
  // VMEM order per slot: D'(tarr,1) B(repoison,1) C(prefetch,4) F(h-store,1)
  //                      G(out-stores, 4 on owsel, t>0)
  // waits: consume vmcnt(1|5); cell vmcnt(5) [retire D']; repoison-at-L3
  //        vmcnt(4) [retire B]; t==0 uses vmcnt(0) (once, pre-pipeline).
  auto slotf = [&](int t, int g, int growg, char* hbg,
                   float& tcurR, float& tdvR, float& c0R, float& c1R,
                   const float* cwrg, size_t oC, size_t oN, size_t oR,
                   const char* prefA, bool issueC, bool deepW) {
    // ---- consume h_t(g) (prefetched into vp0..3) ----
    if (t > 0) {
      if (owsel && deepW) asm volatile("s_waitcnt vmcnt(5)" ::: "memory");
      else                asm volatile("s_waitcnt vmcnt(1)" ::: "memory");
      __builtin_amdgcn_sched_barrier(0);
      int p0 = badchk(vp0), p1 = badchk(vp1), p2 = badchk(vp2), p3 = badchk(vp3);
      if (p0 | p1 | p2 | p3) {                 // rare: prefetch raced the store
        const char* src = hbg + oC + (size_t)tid * 16;
        int guard = 0;
        do {
          if (++guard > (1 << 16)) break;
          __builtin_amdgcn_s_sleep(1);
          if (p0) asm volatile("global_load_dwordx4 %0, %1, off sc0 sc1" : "=&v"(vp0) : "v"(src) : "memory");
          if (p1) asm volatile("global_load_dwordx4 %0, %1, off sc0 sc1" : "=&v"(vp1) : "v"(src + 4096) : "memory");
          if (p2) asm volatile("global_load_dwordx4 %0, %1, off sc0 sc1" : "=&v"(vp2) : "v"(src + 8192) : "memory");
          if (p3) asm volatile("global_load_dwordx4 %0, %1, off sc0 sc1" : "=&v"(vp3) : "v"(src + 12288) : "memory");
          asm volatile("s_waitcnt vmcnt(0)" ::: "memory");
          __builtin_amdgcn_sched_barrier(0);
          p0 = badchk(vp0); p1 = badchk(vp1); p2 = badchk(vp2); p3 = badchk(vp3);
        } while (p0 | p1 | p2 | p3);
      }
      // scatter into hlds (swizzled)
      {
        const int c = tid & 63;
        { int rr = wv;      *(u32x4*)((char*)hlds + (size_t)rr * 1024 + (size_t)((c ^ (rr & 7)) * 16)) = vp0; }
        { int rr = wv + 4;  *(u32x4*)((char*)hlds + (size_t)rr * 1024 + (size_t)((c ^ (rr & 7)) * 16)) = vp1; }
        { int rr = wv + 8;  *(u32x4*)((char*)hlds + (size_t)rr * 1024 + (size_t)((c ^ (rr & 7)) * 16)) = vp2; }
        { int rr = wv + 12; *(u32x4*)((char*)hlds + (size_t)rr * 1024 + (size_t)((c ^ (rr & 7)) * 16)) = vp3; }
      }
      asm volatile("s_waitcnt lgkmcnt(0)" ::: "memory");
      __builtin_amdgcn_s_barrier();           // B4 (raw: no vmcnt drain!)
      #pragma unroll
      for (int kk = 0; kk < 16; ++kk) {
        int kb = kk * 64 + koff;
        afrag[kk] = *(const short8*)((const char*)hlds + (size_t)arow * 1024 + (kb ^ asw));
      }
    } else {
      short8 z = {0, 0, 0, 0, 0, 0, 0, 0};
      #pragma unroll
      for (int kk = 0; kk < 16; ++kk) afrag[kk] = z;     // h_0 = 0
    }

    // ---- D': tarr load (oldest VMEM of the slot) ----
    float tnv;
    {
      int tn_t = (t + 1 < SD) ? (t + 1) : t;
      const char* ta = (const char*)(tarr + (size_t)tn_t * BD + growg);
      asm volatile("global_load_dword %0, %1, off" : "=&v"(tnv) : "v"(ta) : "memory");
    }
    // ---- B: re-poison h_{t-1}'s slot (justified: consume validated h_t) ----
    {
      char* pp = hbg + oR + (size_t)m * 1024 + (size_t)tid * 4;
      unsigned int s = SENT;
      asm volatile("global_store_dword %0, %1, off sc0 sc1" :: "v"(pp), "v"(s) : "memory");
    }

    // ---- gates = h_t @ Whh_slice^T (Wlds, round 6 verbatim) ----
    f32x4 acc0 = {0.f, 0.f, 0.f, 0.f}, acc1 = {0.f, 0.f, 0.f, 0.f};
    #pragma unroll
    for (int kk = 0; kk < 16; ++kk) {
      int kb = kk * 64 + koff;
      short8 b0 = *(const short8*)((const char*)Wlds + (size_t)row0 * 1024 + (kb ^ sw0));
      short8 b1 = *(const short8*)((const char*)Wlds + (size_t)row1 * 1024 + (kb ^ sw1));
      acc0 = __builtin_amdgcn_mfma_f32_16x16x32_bf16(afrag[kk], b0, acc0, 0, 0, 0);
      acc1 = __builtin_amdgcn_mfma_f32_16x16x32_bf16(afrag[kk], b1, acc1, 0, 0, 0);
    }
    {
      int rr = (lane >> 4) * 4, cc = lane & 15;
      #pragma unroll
      for (int qq = 0; qq < 4; ++qq) {
        gbuf[wv][rr + qq][cc]      = acc0[qq];
        gbuf[wv][rr + qq][16 + cc] = acc1[qq];
      }
    }
    asm volatile("s_waitcnt lgkmcnt(0)" ::: "memory");
    __builtin_amdgcn_s_barrier();             // B1 (raw)

    // ---- C: prefetch next slot's h (4 x dwordx4, stay in flight) ----
    if (issueC) {
      asm volatile(
          "global_load_dwordx4 %0, %4, off sc0 sc1\n\t"
          "global_load_dwordx4 %1, %5, off sc0 sc1\n\t"
          "global_load_dwordx4 %2, %6, off sc0 sc1\n\t"
          "global_load_dwordx4 %3, %7, off sc0 sc1"
          : "=&v"(vp0), "=&v"(vp1), "=&v"(vp2), "=&v"(vp3)
          : "v"(prefA), "v"(prefA + 4096), "v"(prefA + 8192), "v"(prefA + 12288)
          : "memory");
    }

    // ---- cell (needs D' => retire oldest with counted wait) ----
    if (t == 0) asm volatile("s_waitcnt vmcnt(0)" ::: "memory");
    else        asm volatile("s_waitcnt vmcnt(5)" ::: "memory");
    __builtin_amdgcn_sched_barrier(0);
    unsigned int hp;
    {
      float p0i = gbuf[0][r][jl0]     + cwrg[0] + tdvR * ur[0];
      float p1i = gbuf[0][r][jl0 + 1] + cwrg[1] + tdvR * ur[1];
      float p0f = gbuf[1][r][jl0]     + cwrg[2] + tdvR * ur[2];
      float p1f = gbuf[1][r][jl0 + 1] + cwrg[3] + tdvR * ur[3];
      float p0g = gbuf[2][r][jl0]     + cwrg[4] + tdvR * ur[4];
      float p1g = gbuf[2][r][jl0 + 1] + cwrg[5] + tdvR * ur[5];
      float p0o = gbuf[3][r][jl0]     + cwrg[6] + tdvR * ur[6];
      float p1o = gbuf[3][r][jl0 + 1] + cwrg[7] + tdvR * ur[7];
      c0R = sigm(p0f) * c0R + sigm(p0i) * tanhf_(p0g);
      c1R = sigm(p1f) * c1R + sigm(p1i) * tanhf_(p1g);
      float h0 = sigm(p0o) * tanhf_(c0R);
      float h1 = sigm(p1o) * tanhf_(c1R);
      hp = (unsigned int)f2bf(h0) | ((unsigned int)f2bf(h1) << 16);
    }

    // ---- repoison must be AT L3 before my h-store (counted: retire B) ----
    if (t == 0) asm volatile("s_waitcnt vmcnt(0)" ::: "memory");
    else        asm volatile("s_waitcnt vmcnt(4)" ::: "memory");
    __builtin_amdgcn_sched_barrier(0);

    // ---- F: h_{t+1} store ----
    {
      char* hs = hbg + oN + (size_t)(r * HD + m * 32 + jl0) * 2;
      asm volatile("global_store_dword %0, %1, off sc0 sc1" :: "v"(hs), "v"(hp) : "memory");
    }

    // ---- out row t-1 (afrag = h_t); after F so peers aren't delayed ----
    if (owsel && t > 0) {
      f32x4 osA = {0.f, 0.f, 0.f, 0.f}, osB = {0.f, 0.f, 0.f, 0.f};
      #pragma unroll
      for (int kk = 0; kk < 8; ++kk) {
        osA = __builtin_amdgcn_mfma_f32_16x16x32_bf16(afrag[kk],     lw[kk],     osA, 0, 0, 0);
        osB = __builtin_amdgcn_mfma_f32_16x16x32_bf16(afrag[kk + 8], lw[kk + 8], osB, 0, 0, 0);
      }
      float* ob = out + (size_t)(t - 1) * (BD * OD) + (size_t)(g * 16) * OD + m * 16;
      int rr = (lane >> 4) * 4, cc = lane & 15;
      #pragma unroll
      for (int qq = 0; qq < 4; ++qq) {
        float vst = osA[qq] + osB[qq] + lb;
        float* oa = ob + (size_t)(rr + qq) * OD + cc;
        asm volatile("global_store_dword %0, %1, off" :: "v"(oa), "v"(vst) : "memory");
      }
    }

    // ---- advance time delta ----
    tdvR  = tnv - tcurR;
    tcurR = tnv;
  };

  for (int t = 0; t < SD; ++t) {
    const int sC = t % 3;
    const int sN = (sC + 1 == 3) ? 0 : sC + 1;
    const int sR = (sN + 1 == 3) ? 0 : sN + 1;
    const size_t oC = (size_t)sC * 16384;
    const size_t oN = (size_t)sN * 16384;
    const size_t oR = (size_t)sR * 16384;

    // slot (g0, t): prefetch h_t(g1) [stored >=1 slot ago: safe]
    slotf(t, g0, grow0, hb0, tcur0, tdv0, c00, c01, cwr0, oC, oN, oR,
          hb1 + oC + (size_t)tid * 16, (t > 0), (t >= 2));
    // slot (g1, t): prefetch h_{t+1}(g0) [stored this step: retry covers]
    slotf(t, g1, grow1, hb1, tcur1, tdv1, c10, c11, cwr1, oC, oN, oR,
          hb0 + oN + (size_t)tid * 16, true, (t >= 1));
  }

  // ---- tail: out row SD-1 = h_SD @ linW^T (wsel waves only; no barriers) ----
  if (owsel) {
    asm volatile("s_waitcnt vmcnt(0)" ::: "memory");
    __builtin_amdgcn_sched_barrier(0);
    #pragma unroll
    for (int gi = 0; gi < 2; ++gi) {
      char* hbg = gi ? hb1 : hb0;
      int   g   = gi ? g1  : g0;
      const char* base = hbg + 2 * 16384 +
          (size_t)(arow * HD) * 2 + (size_t)(lane >> 4) * 16;
      int guard = 0;
      for (;;) {
        #pragma unroll
        for (int b4 = 0; b4 < 4; ++b4) {
          asm volatile(
              "global_load_dwordx4 %0, %4, off sc0 sc1\n\t"
              "global_load_dwordx4 %1, %5, off sc0 sc1\n\t"
              "global_load_dwordx4 %2, %6, off sc0 sc1\n\t"
              "global_load_dwordx4 %3, %7, off sc0 sc1"
              : "=&v"(afrag[b4 * 4]), "=&v"(afrag[b4 * 4 + 1]),
                "=&v"(afrag[b4 * 4 + 2]), "=&v"(afrag[b4 * 4 + 3])
              : "v"(base + (b4 * 4 + 0) * 64), "v"(base + (b4 * 4 + 1) * 64),
                "v"(base + (b4 * 4 + 2) * 64), "v"(base + (b4 * 4 + 3) * 64)
              : "memory");
        }
        asm volatile("s_waitcnt vmcnt(0)" ::: "memory");
        __builtin_amdgcn_sched_barrier(0);
        int bad = 0;
        #pragma unroll
        for (int kk = 0; kk < 16; ++kk) bad |= badchk8(afrag[kk]);
        if (!bad) break;
        if (++guard > (1 << 16)) break;
        __builtin_amdgcn_s_sleep(1);
      }
      f32x4 osA = {0.f, 0.f, 0.f, 0.f}, osB = {0.f, 0.f, 0.f, 0.f};
      #pragma unroll
      for (int kk = 0; kk < 8; ++kk) {
        osA = __builtin_amdgcn_mfma_f32_16x16x32_bf16(afrag[kk],     lw[kk],     osA, 0, 0, 0);
        osB = __builtin_amdgcn_mfma_f32_16x16x32_bf16(afrag[kk + 8], lw[kk + 8], osB, 0, 0, 0);
      }
      float* ob = out + (size_t)(SD - 1) * (BD * OD) + (size_t)(g * 16) * OD + m * 16;
      int rr = (lane >> 4) * 4, cc = lane & 15;
      #pragma unroll
      for (int qq = 0; qq < 4; ++qq) {
        float vst = osA[qq] + osB[qq] + lb;
        float* oa = ob + (size_t)(rr + qq) * OD + cc;
        asm volatile("global_store_dword %0, %1, off" :: "v"(oa), "v"(vst) : "memory");
      }
    }
  }
}

// ---------------- launcher ----------------
extern "C" void kernel_launch(void* const* d_in, const int* in_sizes, int n_in,
                              void* d_out, int out_size, void* d_ws, size_t ws_size,
                              hipStream_t stream) {
  const float* C    = (const float*)d_in[0];
  const float* t    = (const float*)d_in[1];
  // d_in[2] = mask (unused by reference)
  const float* Wih  = (const float*)d_in[3];
  const float* Whh  = (const float*)d_in[4];
  const float* bih  = (const float*)d_in[5];
  const float* bhh  = (const float*)d_in[6];
  const float* linW = (const float*)d_in[7];
  const float* linb = (const float*)d_in[8];
  const float* tW   = (const float*)d_in[9];
  const float* tb   = (const float*)d_in[10];
  float* out = (float*)d_out;

  char* ws = (char*)d_ws;
  float*          CW    = (float*)(ws + 0);                 // 2,097,152
  float*          u     = (float*)(ws + 2097152);           // 8,192
  float*          ub    = (float*)(ws + 2105344);           // 8,192
  unsigned short* whhb  = (unsigned short*)(ws + 2113536);  // 2,097,152
  unsigned short* linwb = (unsigned short*)(ws + 4210688);  // 131,072
  unsigned short* hbuf  = (unsigned short*)(ws + 4341760);  // 16*3*16*512*2 = 786,432
  if (ws_size < 5128192) return;

  k_poison<<<192, 256, 0, stream>>>((unsigned int*)hbuf);
  k_cvt<<<4096, 256, 0, stream>>>(Whh, linW, whhb, linwb);
  k_u  <<<8, 256, 0, stream>>>(Wih, tW, tb, bih, bhh, u, ub);
  k_cw <<<dim3(32, 16), 1024, 0, stream>>>(C, Wih, ub, CW);
  k_main<<<128, 256, 0, stream>>>(CW, u, t, whhb, linwb, linb, hbuf, out);
}